// Round 3
// baseline (135.702 us; speedup 1.0000x reference)
//
#include <hip/hip_runtime.h>

// PointSIFT: octant-wise nearest neighbor within radius + group. Fused kernel.
// B=2, N=4096, C=64 fixed by the problem.
#define BB 2
#define NN 4096
#define CC 64
#define QPB 16              // queries per block
#define TPQ 16              // threads per query (one candidate stripe each)
#define NT (QPB * TPQ)      // 256 threads per block

// flat output layout (all float32):
//   out0 grouped_xyz   [B,N,8,3]
//   out1 grouped_points[B,N,8,67]
//   out2 idx (as float)[B,N,8]
#define OUT0_OFF 0
#define OUT1_OFF (BB * NN * 8 * 3)               /* 196608 */
#define OUT2_OFF (OUT1_OFF + BB * NN * 8 * 67)   /* 4587520 */

__global__ __launch_bounds__(NT) void pointsift_fused(
    const float* __restrict__ xyz, const float* __restrict__ points,
    const float* __restrict__ radius_p, float* __restrict__ out)
{
    __shared__ float s_xyz4[NN * 4];          // 64 KiB: padded float4 coords
    __shared__ int   s_sel[QPB * 8];          // selected idx per (query,octant)

    const int tid = threadIdx.x;
    const int blocks_per_batch = NN / QPB;    // 256
    const int b = blockIdx.x / blocks_per_batch;
    const int qbase = (blockIdx.x % blocks_per_batch) * QPB;

    // stage this batch's xyz into LDS, padded to float4 stride
    {
        const float* src = xyz + (size_t)b * NN * 3;
        for (int p = tid; p < NN; p += NT) {
            float x = src[p * 3 + 0];
            float y = src[p * 3 + 1];
            float z = src[p * 3 + 2];
            float4* d = (float4*)(s_xyz4 + p * 4);
            *d = make_float4(x, y, z, 0.0f);
        }
    }

    const float r = radius_p[0];
    const float judge = __fmul_rn(r, r);

    const int n = qbase + (tid >> 4);         // query index within batch
    const int sub = tid & (TPQ - 1);          // candidate stripe id

    __syncthreads();

    const float qx = s_xyz4[n * 4 + 0];
    const float qy = s_xyz4[n * 4 + 1];
    const float qz = s_xyz4[n * 4 + 2];

    // register scoreboard, seeded with the diagonal entry (judge, n)
    float bd[8]; int bi[8];
    #pragma unroll
    for (int o = 0; o < 8; ++o) { bd[o] = judge; bi[o] = n; }

    // scan candidate stripe p = sub, sub+16, ... (ascending -> first-min kept)
    const float4* sx4 = (const float4*)s_xyz4;
    #pragma unroll 8
    for (int p = sub; p < NN; p += TPQ) {
        float4 c = sx4[p];
        // diff = candidate - query, fp32, no contraction (must match numpy ref)
        float dx = __fsub_rn(c.x, qx);
        float dy = __fsub_rn(c.y, qy);
        float dz = __fsub_rn(c.z, qz);
        float dist = __fadd_rn(__fadd_rn(__fmul_rn(dx, dx), __fmul_rn(dy, dy)),
                               __fmul_rn(dz, dz));
        // Octant bit = (int)(d + 1.0f) per the ref. Within the valid region
        // (dist < judge <= 0.0625 -> |d| < 0.25 -> d+1.0f in (0.75,1.25)) the
        // truncated int is exactly (d+1.0f >= 1.0f). Invalid candidates are
        // masked out below, so the boolean form is exact where it matters.
        bool gx = __fadd_rn(dx, 1.0f) >= 1.0f;
        bool gy = __fadd_rn(dy, 1.0f) >= 1.0f;
        bool gz = __fadd_rn(dz, 1.0f) >= 1.0f;
        bool valid = (dist < judge) & (dist > 1e-10f);
        // per-octant update: mask combine is SALU (s_and/s_andn2), update is
        // v_cmp_lt + 2 v_cndmask -> ~3 VALU per octant
        #pragma unroll
        for (int o = 0; o < 8; ++o) {
            bool m = valid
                   & ((o & 4) ? gx : !gx)
                   & ((o & 2) ? gy : !gy)
                   & ((o & 1) ? gz : !gz)
                   & (dist < bd[o]);
            bd[o] = m ? dist : bd[o];
            bi[o] = m ? p    : bi[o];
        }
    }

    // butterfly reduce over the 16 stripe-threads of this query
    // (lanes are 16-aligned within the wave); tie-break: smaller index wins
    #pragma unroll
    for (int m = 1; m < TPQ; m <<= 1) {
        #pragma unroll
        for (int o = 0; o < 8; ++o) {
            float od = __shfl_xor(bd[o], m, 64);
            int   oi = __shfl_xor(bi[o], m, 64);
            if (od < bd[o] || (od == bd[o] && oi < bi[o])) {
                bd[o] = od; bi[o] = oi;
            }
        }
    }

    // publish selected indices to LDS (lanes sub<8 each publish one octant)
    if (sub < 8) s_sel[(tid >> 4) * 8 + sub] = bi[sub];
    __syncthreads();

    // fused gather: wave per (query,octant) pair; lane c handles channel c.
    // QPB*8 = 128 pairs, 4 waves/block -> 32 iterations each.
    const int wave = tid >> 6;
    const int lane = tid & 63;
    const float* prow = points + (size_t)b * NN * CC;
    for (int pid = wave; pid < QPB * 8; pid += NT / 64) {
        const int q = pid >> 3;
        const int o = pid & 7;
        const int i = s_sel[pid];
        const int nq = qbase + q;
        const size_t rest = ((size_t)b * NN + nq) * 8 + o;
        // features: lane c -> out1[rest*67 + 3 + c]
        float f = prow[(size_t)i * CC + lane];
        out[OUT1_OFF + rest * 67 + 3 + lane] = f;
        if (lane < 3) {
            float g = __fsub_rn(s_xyz4[i * 4 + lane], s_xyz4[nq * 4 + lane]);
            out[OUT0_OFF + rest * 3 + lane] = g;
            out[OUT1_OFF + rest * 67 + lane] = g;
        } else if (lane == 3) {
            out[OUT2_OFF + rest] = (float)i;  // idx as float
        }
    }
}

extern "C" void kernel_launch(void* const* d_in, const int* in_sizes, int n_in,
                              void* d_out, int out_size, void* d_ws, size_t ws_size,
                              hipStream_t stream) {
    const float* xyz    = (const float*)d_in[0];
    const float* points = (const float*)d_in[1];
    const float* radius = (const float*)d_in[2];
    float* out = (float*)d_out;

    hipLaunchKernelGGL(pointsift_fused, dim3(BB * NN / QPB), dim3(NT), 0, stream,
                       xyz, points, radius, out);
}